// Round 13
// baseline (24.823 us; speedup 1.0000x reference)
//
#include <hip/hip_runtime.h>

// Problem constants
#define BB 4
#define LL 512
#define WW 256
#define EE 300
#define HH 768

typedef __attribute__((ext_vector_type(8))) short bf16x8;
typedef __attribute__((ext_vector_type(4))) float f32x4;

__device__ __forceinline__ short f2bf(float f) {
    union { float f; unsigned u; } v; v.f = f;
    unsigned r = (v.u + 0x7FFFu + ((v.u >> 16) & 1u)) >> 16;
    return (short)r;
}

// ---------------------------------------------------------------------------
// kA: blocks 0..191: aT = (emb_a[word_seq] @ lin_w + lin_b), bf16, k-major
//     aT[b][h/8][w][h%8] (R8-verified body). Blocks 192..319: convert
//     hidden f32 -> hidb bf16 (16 rows each) so kB reads half the bytes.
// ---------------------------------------------------------------------------
__global__ __launch_bounds__(256, 1) void kA_prep(
    const int*   __restrict__ word_seq,
    const float* __restrict__ emb_a,
    const float* __restrict__ lin_w,
    const float* __restrict__ lin_b,
    const float* __restrict__ hidden,
    short*       __restrict__ aT,      // [4][96][256][8] bf16
    short*       __restrict__ hidb)    // [2048][768] bf16
{
    const int t = threadIdx.x;

    if (blockIdx.x >= 192) {
        // ---- hidden conversion: 128 blocks x 16 rows ----
        const int  cb   = blockIdx.x - 192;
        const long base = (long)cb * 16 * HH;
#pragma unroll
        for (int j = 0; j < 6; ++j) {
            const long idx = base + (long)(t + j * 256) * 8;
            const float4 p0 = *(const float4*)(hidden + idx);
            const float4 p1 = *(const float4*)(hidden + idx + 4);
            bf16x8 v;
            v[0] = f2bf(p0.x); v[1] = f2bf(p0.y); v[2] = f2bf(p0.z); v[3] = f2bf(p0.w);
            v[4] = f2bf(p1.x); v[5] = f2bf(p1.y); v[6] = f2bf(p1.z); v[7] = f2bf(p1.w);
            *(bf16x8*)(hidb + idx) = v;
        }
        return;
    }

    __shared__ short eaL[2][64 * 168];   // [half][m-row][k] bf16, stride 168
    __shared__ short lwL[2][64 * 168];   // [half][n-row(h)][k]

    const int m0 = (blockIdx.x & 15) * 64;
    const int n0 = (blockIdx.x >> 4) * 64;

    const int lane = t & 63, wv = t >> 6;
    const int l15 = lane & 15, l4 = lane >> 4;

    const int r_ea = t >> 2;             // 0..63 m-row
    const int q_ea = t & 3;              // quarter of the 160-wide half
    const int h_lw = t & 63;             // n-row
    const int q_lw = t >> 6;             // quarter

    const int    wrow = word_seq[m0 + r_ea];
    const float* arow = emb_a + (long)wrow * EE;

    f32x4 acc[4] = {};
    float ea_reg[40], lw_reg[40];

#pragma unroll
    for (int half = 0; half < 2; ++half) {
        const int k0 = half * 160;
        {
            const int cbase = k0 + q_ea * 40;
#pragma unroll
            for (int c4 = 0; c4 < 10; ++c4) {
                const int col = cbase + c4 * 4;
                if (col <= 296) {
                    const float4 p = *(const float4*)(arow + col);
                    ea_reg[c4 * 4 + 0] = p.x; ea_reg[c4 * 4 + 1] = p.y;
                    ea_reg[c4 * 4 + 2] = p.z; ea_reg[c4 * 4 + 3] = p.w;
                } else {
                    ea_reg[c4 * 4 + 0] = 0.f; ea_reg[c4 * 4 + 1] = 0.f;
                    ea_reg[c4 * 4 + 2] = 0.f; ea_reg[c4 * 4 + 3] = 0.f;
                }
            }
            const int cb2 = k0 + q_lw * 40;
#pragma unroll
            for (int j = 0; j < 40; ++j) {
                const int col = cb2 + j;
                lw_reg[j] = (col < EE) ? lin_w[(long)col * HH + n0 + h_lw] : 0.f;
            }
        }
        {
            const int eoff = r_ea * 168 + q_ea * 40;
#pragma unroll
            for (int c8 = 0; c8 < 5; ++c8) {
                bf16x8 sv;
#pragma unroll
                for (int j = 0; j < 8; ++j) sv[j] = f2bf(ea_reg[c8 * 8 + j]);
                *(bf16x8*)(&eaL[half][eoff + c8 * 8]) = sv;
            }
            const int loff = h_lw * 168 + q_lw * 40;
#pragma unroll
            for (int c8 = 0; c8 < 5; ++c8) {
                bf16x8 sv;
#pragma unroll
                for (int j = 0; j < 8; ++j) sv[j] = f2bf(lw_reg[c8 * 8 + j]);
                *(bf16x8*)(&lwL[half][loff + c8 * 8]) = sv;
            }
        }
        __syncthreads();
#pragma unroll
        for (int ks = 0; ks < 5; ++ks) {
            const bf16x8 af =
                *(const bf16x8*)(&eaL[half][(wv * 16 + l15) * 168 + ks * 32 + l4 * 8]);
#pragma unroll
            for (int nf = 0; nf < 4; ++nf) {
                const bf16x8 bfv =
                    *(const bf16x8*)(&lwL[half][(nf * 16 + l15) * 168 + ks * 32 + l4 * 8]);
                acc[nf] = __builtin_amdgcn_mfma_f32_16x16x32_bf16(af, bfv, acc[nf], 0, 0, 0);
            }
        }
    }

    const int b1 = m0 >> 8;
#pragma unroll
    for (int nf = 0; nf < 4; ++nf) {
        const int h    = n0 + nf * 16 + l15;
        const float bv = lin_b[h];
        const long hbase = ((long)(b1 * 96 + (h >> 3)) * WW) * 8 + (h & 7);
#pragma unroll
        for (int i = 0; i < 4; ++i) {
            const int w = (m0 & 255) + wv * 16 + l4 * 4 + i;
            aT[hbase + (long)w * 8] = f2bf(acc[nf][i] + bv);
        }
    }
}

// ---------------------------------------------------------------------------
// kB: u-GEMM + bucket partial sums. Block = (b, 32 l-rows, 64 w) -> per-CU
// bytes: 96KB aT + 49KB hidb + 8KB label ~= 155KB (vs R8's ~450KB), the
// per-CU-BW model's main lever. 256 blocks x 512 thr, 8 waves:
// wave = (k-half kh, w-quarter wq); each wave 2 m-frags x 12 k-steps;
// kh=1 waves dump acc to LDS, kh=0 waves combine + softmax-bucket partials
// -> s_part[row][ws*5+c].
// ---------------------------------------------------------------------------
__global__ __launch_bounds__(512, 1) void kB_attn(
    const short* __restrict__ hidb,     // [2048][768] bf16
    const int*   __restrict__ label,    // [4][512][256]
    const short* __restrict__ aT,       // [4][96][256][8] bf16
    float*       __restrict__ s_part)   // [2048][4][5] f32
{
    __shared__ short hid[32 * 776];          // 49.7 KB
    __shared__ float accx[4][64][8];         // 8 KB (kh=1 partial accs)
    __shared__ float s_lds[4][2][16][5];     // 2.5 KB

    const int t = threadIdx.x, lane = t & 63, wv = t >> 6;   // wv 0..7
    const int l15 = lane & 15, l4 = lane >> 4;
    const int bid = blockIdx.x;
    const int lt = bid & 15, ws = (bid >> 4) & 3, b = bid >> 6;
    const int row0 = b * 512 + lt * 32;
    const int kh = wv >> 2, wq = wv & 3;
    const int wg = ws * 64 + wq * 16 + l15;      // this lane's global w

    // ---- stage 32 hid rows (bf16, direct copy) ----
    {
        const short* hrow = hidb + (long)row0 * HH;
#pragma unroll
        for (int j = 0; j < 3; ++j) {
            const int ci  = t + j * 512;         // 0..1535
            const int row = ci / 96;
            const int col = (ci - row * 96) * 8;
            *(bf16x8*)(&hid[row * 776 + col]) =
                *(const bf16x8*)(hrow + (long)row * HH + col);
        }
    }

    // ---- labels (kh=0 waves only; consumed post-GEMM) ----
    int lv[2][4];
    if (kh == 0) {
#pragma unroll
        for (int mf = 0; mf < 2; ++mf)
#pragma unroll
            for (int i = 0; i < 4; ++i)
                lv[mf][i] = label[((long)row0 + mf * 16 + l4 * 4 + i) * WW + wg];
    }
    __syncthreads();

    // ---- u GEMM: this wave's 12 k-steps, no barriers ----
    const short* abase = aT + (long)b * 96 * WW * 8;
    f32x4 acc[2] = {};
#pragma unroll
    for (int kk = 0; kk < 12; ++kk) {
        const int ks = kh * 12 + kk;
        const bf16x8 bfv =
            *(const bf16x8*)(abase + ((long)(ks * 4 + l4) * WW + wg) * 8);
        const bf16x8 a0 = *(const bf16x8*)(&hid[l15 * 776 + ks * 32 + l4 * 8]);
        const bf16x8 a1 = *(const bf16x8*)(&hid[(16 + l15) * 776 + ks * 32 + l4 * 8]);
        acc[0] = __builtin_amdgcn_mfma_f32_16x16x32_bf16(a0, bfv, acc[0], 0, 0, 0);
        acc[1] = __builtin_amdgcn_mfma_f32_16x16x32_bf16(a1, bfv, acc[1], 0, 0, 0);
    }

    if (kh == 1) {
#pragma unroll
        for (int mf = 0; mf < 2; ++mf)
#pragma unroll
            for (int i = 0; i < 4; ++i)
                accx[wq][lane][mf * 4 + i] = acc[mf][i];
    }
    __syncthreads();

    if (kh == 0) {
        // combine k-halves
#pragma unroll
        for (int mf = 0; mf < 2; ++mf)
#pragma unroll
            for (int i = 0; i < 4; ++i)
                acc[mf][i] += accx[wq][lane][mf * 4 + i];

        // exp + masked label-bucket accumulation
        const float inv_temper = 0.03608439182435161f;   // 1/sqrt(768)
        float s_loc[2][4][5];
#pragma unroll
        for (int mf = 0; mf < 2; ++mf)
#pragma unroll
            for (int i = 0; i < 4; ++i) {
                const float e = __expf(acc[mf][i] * inv_temper);
#pragma unroll
                for (int c = 1; c <= 5; ++c)
                    s_loc[mf][i][c - 1] = (lv[mf][i] == c) ? e : 0.f;
            }
        // reduce across the 16 lanes (w) sharing the same l4 group
#pragma unroll
        for (int mf = 0; mf < 2; ++mf)
#pragma unroll
            for (int i = 0; i < 4; ++i)
#pragma unroll
                for (int c = 0; c < 5; ++c) {
                    float v = s_loc[mf][i][c];
                    v += __shfl_xor(v, 1);
                    v += __shfl_xor(v, 2);
                    v += __shfl_xor(v, 4);
                    v += __shfl_xor(v, 8);
                    s_loc[mf][i][c] = v;
                }
        if (l15 == 0) {
#pragma unroll
            for (int mf = 0; mf < 2; ++mf)
#pragma unroll
                for (int i = 0; i < 4; ++i)
#pragma unroll
                    for (int c = 0; c < 5; ++c)
                        s_lds[wq][mf][l4 * 4 + i][c] = s_loc[mf][i][c];
        }
    }
    __syncthreads();

    if (t < 32) {      // t = row offset 0..31
#pragma unroll
        for (int c = 0; c < 5; ++c) {
            const float s = s_lds[0][t >> 4][t & 15][c] + s_lds[1][t >> 4][t & 15][c] +
                            s_lds[2][t >> 4][t & 15][c] + s_lds[3][t >> 4][t & 15][c];
            s_part[((long)row0 + t) * 20 + ws * 5 + c] = s;
        }
    }
}

// ---------------------------------------------------------------------------
// k3: output. 512 blocks x 256 thr, 4 rows each:
// o[row][h] = (sum_c s_c * emb_c[c][h]) / (sum_c s_c + 1e-10),
// s_c = sum of the 4 w-split partials.
// ---------------------------------------------------------------------------
__global__ __launch_bounds__(256) void k3_out(
    const float* __restrict__ s_part,   // [2048][4][5]
    const float* __restrict__ emb_c,    // [6][768]
    float*       __restrict__ out)      // [2048][768]
{
    const int t  = threadIdx.x;
    const int r0 = blockIdx.x * 4;

    float ecv[3][5];
#pragma unroll
    for (int q = 0; q < 3; ++q)
#pragma unroll
        for (int c = 0; c < 5; ++c)
            ecv[q][c] = emb_c[(c + 1) * HH + t + q * 256];

#pragma unroll
    for (int r = 0; r < 4; ++r) {
        const int row = r0 + r;
        const long sb = (long)row * 20;
        float s[5], den = 1e-10f;
#pragma unroll
        for (int c = 0; c < 5; ++c) {
            s[c] = s_part[sb + c] + s_part[sb + 5 + c] +
                   s_part[sb + 10 + c] + s_part[sb + 15 + c];
            den += s[c];
        }
        const float id = 1.0f / den;
        float* orow = out + (long)row * HH;
#pragma unroll
        for (int q = 0; q < 3; ++q) {
            const float v = s[0] * ecv[q][0] + s[1] * ecv[q][1] + s[2] * ecv[q][2] +
                            s[3] * ecv[q][3] + s[4] * ecv[q][4];
            orow[t + q * 256] = v * id;
        }
    }
}

extern "C" void kernel_launch(void* const* d_in, const int* in_sizes, int n_in,
                              void* d_out, int out_size, void* d_ws, size_t ws_size,
                              hipStream_t stream) {
    const int*   word_seq = (const int*)  d_in[0];
    const float* hidden   = (const float*)d_in[1];
    const int*   label    = (const int*)  d_in[2];
    const float* emb_a    = (const float*)d_in[3];
    const float* lin_w    = (const float*)d_in[4];
    const float* lin_b    = (const float*)d_in[5];
    const float* emb_c    = (const float*)d_in[6];
    float* out = (float*)d_out;

    short* aT     = (short*)d_ws;                      // 1.5 MB
    short* hidb   = aT + (long)4 * 96 * WW * 8;        // 3 MB
    float* s_part = (float*)(hidb + (long)2048 * HH);  // 160 KB

    kA_prep<<<dim3(320), 256, 0, stream>>>(word_seq, emb_a, lin_w, lin_b,
                                           hidden, aT, hidb);
    kB_attn<<<dim3(256), 512, 0, stream>>>(hidb, label, aT, s_part);
    k3_out<<<dim3(512), 256, 0, stream>>>(s_part, emb_c, out);
}